// Round 24
// baseline (34.938 us; speedup 1.0000x reference)
//
#include <hip/hip_runtime.h>
#include <hip/hip_bf16.h>

// InferenceLinear: out[m][n] = sum_k x[m][k] * (q[n][k]*qrange[n][k/256] + qmin[n][k/256])
// M=512, N=2048, K=4096, 16 groups of 256.
// R23 resubmit (infra failure, no signal). = R22 champion (32.2us) with ONE
// isolated change: nontemporal hints on the GEMM's bf16 partial STORES only.
// Theory: per-XCD L2 working set = operands 2.5MB + partials writes 2.1MB =
// 4.6MB > 4MB -> operand re-reads fall to L3 (~10TB/s, explains GEMM ~16us).
// NT stores keep partials out of L2 -> re-reads L2-served.

#define M_T 512
#define N_T 2048
#define K_T 4096
#define NGRP 16
#define BM 128
#define BN 128
#define BK 64
#define OUT_ELEMS (M_T * N_T)
#define W_ELEMS (N_T * K_T)          // 8388608 bf16
#define X_ELEMS (M_T * K_T)          // 2097152 bf16

typedef __attribute__((ext_vector_type(8))) short mfrag_t;           // 8 bf16 (4 VGPR)
typedef __attribute__((ext_vector_type(8))) unsigned short u16x8;
typedef __attribute__((ext_vector_type(4))) float f32x4;

__device__ __forceinline__ unsigned short f2bf(float f) {
  union { __hip_bfloat16 h; unsigned short u; } c;
  c.h = __float2bfloat16(f);
  return c.u;
}

__device__ __forceinline__ float bf2f(unsigned short u) {
  union { unsigned int i; float f; } c;
  c.i = ((unsigned int)u) << 16;
  return c.f;
}

// ---- pass 1: dequant W (int32 q -> bf16) + cast X (fp32 -> bf16) ----
__global__ __launch_bounds__(256) void pack_kernel(
    const float* __restrict__ x, const int* __restrict__ qw,
    const float* __restrict__ qrange, const float* __restrict__ qmin,
    unsigned short* __restrict__ wsW, unsigned short* __restrict__ wsX) {
  const int bid = blockIdx.x;
  const int tid = threadIdx.x;
  if (bid < (W_ELEMS / 8) / 256) {
    const int gidx = bid * 256 + tid;        // [0, 1048576)
    const int o = gidx >> 9;                 // 512 groups-of-8 per row
    const int k8 = gidx & 511;
    const int g = k8 >> 5;                   // 32 groups-of-8 per quant group
    const float sc = qrange[o * NGRP + g];
    const float mn = qmin[o * NGRP + g];
    const int4* q = (const int4*)(qw + ((size_t)o << 12) + (k8 << 3));
    const int4 q0 = q[0], q1 = q[1];
    u16x8 p;
    p[0] = f2bf((float)q0.x * sc + mn); p[1] = f2bf((float)q0.y * sc + mn);
    p[2] = f2bf((float)q0.z * sc + mn); p[3] = f2bf((float)q0.w * sc + mn);
    p[4] = f2bf((float)q1.x * sc + mn); p[5] = f2bf((float)q1.y * sc + mn);
    p[6] = f2bf((float)q1.z * sc + mn); p[7] = f2bf((float)q1.w * sc + mn);
    *(u16x8*)(wsW + ((size_t)gidx << 3)) = p;
  } else {
    const int gidx = (bid - (W_ELEMS / 8) / 256) * 256 + tid;  // [0, 262144)
    const float4* a = (const float4*)(x + ((size_t)gidx << 3));
    const float4 a0 = a[0], a1 = a[1];
    u16x8 p;
    p[0] = f2bf(a0.x); p[1] = f2bf(a0.y); p[2] = f2bf(a0.z); p[3] = f2bf(a0.w);
    p[4] = f2bf(a1.x); p[5] = f2bf(a1.y); p[6] = f2bf(a1.z); p[7] = f2bf(a1.w);
    *(u16x8*)(wsX + ((size_t)gidx << 3)) = p;
  }
}

// ---- pass 2: bf16 GEMM with global_load_lds staging; NT bf16 partial stores ----
template <int KSPLIT, bool XCDSWZ>
__global__ __launch_bounds__(512, 4) void dq_gemm_kernel(
    const unsigned short* __restrict__ wsX, const unsigned short* __restrict__ wsW,
    unsigned short* __restrict__ dst) {
  constexpr int KC = K_T / KSPLIT;
  constexpr int NTC = KC / BK;

  // physical layout: [row][slot^(row&7)], slot = 8-elem (16B) unit; linear fill
  __shared__ __align__(16) unsigned short As[BM * BK];
  __shared__ __align__(16) unsigned short Bs[BN * BK];

  const int tid = threadIdx.x;
  int xt, yt, kc;
  if (XCDSWZ) {
    const int b = blockIdx.x;
    kc = b & 7;                 // XCD id == k-chunk (assumes b%8 round-robin)
    const int slot = b >> 3;
    xt = slot & 15;             // n-tile
    yt = slot >> 4;             // m-tile
  } else {
    const int b = blockIdx.x;
    xt = b & 15;
    yt = (b >> 4) & 3;
    kc = b >> 6;
  }
  const int n0 = xt * BN;
  const int m0 = yt * BM;
  const int kbase = kc * KC;

  // compute mapping: 8 waves, 2(M) x 4(N); wave tile 64x32
  const int lane = tid & 63;
  const int wv = tid >> 6;
  const int wm = (wv >> 2) * 64;   // 0,64
  const int wn = (wv & 3) * 32;    // 0,32,64,96
  const int lr = lane & 15;
  const int lq = lane >> 4;
  const int rxl = lr & 7;  // read-side xor (row&7 == lr&7: wm,wn,f*16 mult of 8)

  // staging mapping for global_load_lds (16B/lane): wave wv covers rows
  // [wv*16, wv*16+16) in two 1KB chunks (8 rows each). lane l -> row += l>>3,
  // phys slot = l&7. LDS[row][p] holds logical data[p ^ (row&7)]; row&7 == l>>3,
  // so per-lane GLOBAL source col16 = (l&7) ^ (l>>3). Dest linear = base+lane*16.
  const int swzcol = (((lane & 7) ^ (lane >> 3)) << 3);       // elem offset
  const int r0 = wv * 16 + (lane >> 3);                        // chunk0 row
  const int r1 = r0 + 8;                                       // chunk1 row
  const unsigned short* gA0 = wsX + (size_t)(m0 + r0) * K_T + kbase + swzcol;
  const unsigned short* gA1 = wsX + (size_t)(m0 + r1) * K_T + kbase + swzcol;
  const unsigned short* gB0 = wsW + (size_t)(n0 + r0) * K_T + kbase + swzcol;
  const unsigned short* gB1 = wsW + (size_t)(n0 + r1) * K_T + kbase + swzcol;
  unsigned short* lA0 = &As[wv * 1024];        // elems; 2KB per wave
  unsigned short* lA1 = &As[wv * 1024 + 512];
  unsigned short* lB0 = &Bs[wv * 1024];
  unsigned short* lB1 = &Bs[wv * 1024 + 512];

#define STAGE(T)                                                              \
  do {                                                                        \
    const size_t o_ = (size_t)(T) * BK;                                       \
    __builtin_amdgcn_global_load_lds(                                         \
        (const __attribute__((address_space(1))) void*)(gA0 + o_),            \
        (__attribute__((address_space(3))) void*)lA0, 16, 0, 0);              \
    __builtin_amdgcn_global_load_lds(                                         \
        (const __attribute__((address_space(1))) void*)(gA1 + o_),            \
        (__attribute__((address_space(3))) void*)lA1, 16, 0, 0);              \
    __builtin_amdgcn_global_load_lds(                                         \
        (const __attribute__((address_space(1))) void*)(gB0 + o_),            \
        (__attribute__((address_space(3))) void*)lB0, 16, 0, 0);              \
    __builtin_amdgcn_global_load_lds(                                         \
        (const __attribute__((address_space(1))) void*)(gB1 + o_),            \
        (__attribute__((address_space(3))) void*)lB1, 16, 0, 0);              \
  } while (0)

  f32x4 acc[4][2] = {};

  STAGE(0);
  for (int t = 0; t < NTC; ++t) {
    __syncthreads();  // drains vmcnt(0): staged tile visible to all waves

#pragma unroll
    for (int kk = 0; kk < 2; ++kk) {
      const int so = ((kk * 4 + lq) ^ rxl) << 3;
      mfrag_t af[4], bf[2];
#pragma unroll
      for (int fm = 0; fm < 4; ++fm)
        af[fm] = *(const mfrag_t*)&As[(wm + fm * 16 + lr) * BK + so];
#pragma unroll
      for (int fn = 0; fn < 2; ++fn)
        bf[fn] = *(const mfrag_t*)&Bs[(wn + fn * 16 + lr) * BK + so];
#pragma unroll
      for (int fm = 0; fm < 4; ++fm)
#pragma unroll
        for (int fn = 0; fn < 2; ++fn)
          acc[fm][fn] = __builtin_amdgcn_mfma_f32_16x16x32_bf16(af[fm], bf[fn], acc[fm][fn], 0, 0, 0);
    }

    if (t + 1 < NTC) {
      __syncthreads();  // all waves done reading before overwrite
      STAGE(t + 1);
    }
  }
#undef STAGE

  // ---- epilogue: NONTEMPORAL bf16 partial stores (keep partials out of L2) ----
  // C/D layout col=lane&15, row=(lane>>4)*4+reg (measured m89/m91)
  unsigned short* base = dst + (size_t)kc * OUT_ELEMS;
#pragma unroll
  for (int fm = 0; fm < 4; ++fm) {
#pragma unroll
    for (int fn = 0; fn < 2; ++fn) {
      const int rr = m0 + wm + fm * 16 + lq * 4;
      const int c = n0 + wn + fn * 16 + lr;
      unsigned short* op = base + (size_t)rr * N_T + c;
      __builtin_nontemporal_store(f2bf(acc[fm][fn][0]), op + 0 * (size_t)N_T);
      __builtin_nontemporal_store(f2bf(acc[fm][fn][1]), op + 1 * (size_t)N_T);
      __builtin_nontemporal_store(f2bf(acc[fm][fn][2]), op + 2 * (size_t)N_T);
      __builtin_nontemporal_store(f2bf(acc[fm][fn][3]), op + 3 * (size_t)N_T);
    }
  }
}

// ---- pass 3: out[i] = sum_s bf16 partials[s][i], fp32 accum, fixed order ----
template <int KSPLIT>
__global__ __launch_bounds__(256) void reduce_kernel(const unsigned short* __restrict__ ws,
                                                     float* __restrict__ out) {
  const int i8 = blockIdx.x * 256 + threadIdx.x;   // 8 elems per thread
  const size_t base = (size_t)i8 * 8;
  float s[8];
  {
    const u16x8 v = *(const u16x8*)(ws + base);
#pragma unroll
    for (int j = 0; j < 8; ++j) s[j] = bf2f(v[j]);
  }
#pragma unroll
  for (int sl = 1; sl < KSPLIT; ++sl) {
    const u16x8 v = *(const u16x8*)(ws + (size_t)sl * OUT_ELEMS + base);
#pragma unroll
    for (int j = 0; j < 8; ++j) s[j] += bf2f(v[j]);
  }
  float4* o = (float4*)(out + base);
  o[0] = make_float4(s[0], s[1], s[2], s[3]);
  o[1] = make_float4(s[4], s[5], s[6], s[7]);
}

// ---- fallback only (never expected to run): naive dot per output elem ----
__global__ void naive_kernel(const float* __restrict__ x, const int* __restrict__ qw,
                             const float* __restrict__ qrange, const float* __restrict__ qmin,
                             float* __restrict__ out) {
  const int idx = blockIdx.x * 256 + threadIdx.x;
  if (idx >= OUT_ELEMS) return;
  const int m = idx / N_T, n = idx % N_T;
  float s = 0.f;
  for (int g = 0; g < NGRP; ++g) {
    const float sc = qrange[n * NGRP + g], mn = qmin[n * NGRP + g];
    float d = 0.f, xs = 0.f;
    for (int k = g * 256; k < (g + 1) * 256; ++k) {
      d += x[(size_t)m * K_T + k] * (float)qw[(size_t)n * K_T + k];
      xs += x[(size_t)m * K_T + k];
    }
    s += d * sc + xs * mn;
  }
  out[idx] = s;
}

extern "C" void kernel_launch(void* const* d_in, const int* in_sizes, int n_in,
                              void* d_out, int out_size, void* d_ws, size_t ws_size,
                              hipStream_t stream) {
  const float* x = (const float*)d_in[0];
  const int* qw = (const int*)d_in[1];
  const float* qr = (const float*)d_in[2];
  const float* qm = (const float*)d_in[3];
  float* out = (float*)d_out;

  constexpr int KS = 8;
  unsigned short* wsW = (unsigned short*)d_ws;
  unsigned short* wsX = wsW + W_ELEMS;
  unsigned short* partials = wsX + X_ELEMS;
  const size_t need = (size_t)W_ELEMS * 2 + (size_t)X_ELEMS * 2 +
                      (size_t)KS * OUT_ELEMS * 2;
  if (ws_size >= need) {
    const int packblk = (W_ELEMS / 8) / 256 + (X_ELEMS / 8) / 256;  // 4096+1024
    pack_kernel<<<packblk, 256, 0, stream>>>(x, qw, qr, qm, wsW, wsX);
    const int nblk = (N_T / BN) * (M_T / BM) * KS;  // 512
    dq_gemm_kernel<KS, true><<<nblk, dim3(512, 1, 1), 0, stream>>>(wsX, wsW, partials);
    reduce_kernel<KS><<<OUT_ELEMS / 8 / 256, 256, 0, stream>>>(partials, out);
  } else {
    naive_kernel<<<(OUT_ELEMS + 255) / 256, 256, 0, stream>>>(x, qw, qr, qm, out);
  }
}

// Round 25
// 34.580 us; speedup vs baseline: 1.0103x; 1.0103x over previous
//
#include <hip/hip_runtime.h>
#include <hip/hip_bf16.h>

// InferenceLinear: out[m][n] = sum_k x[m][k] * (q[n][k]*qrange[n][k/256] + qmin[n][k/256])
// M=512, N=2048, K=4096, 16 groups of 256.
// R25: halve W(B) re-reads — the only L3-resident term left. BM 128->256
// (B-traffic 67->33.6MB, total re-reads 134->100MB). Grid 256 (1/CU, 8 waves of
// 64x64, acc[4][4]); compute:stage ratio doubles so the 2-barrier stall shrinks.
// launch_bounds(512,2) = 256-VGPR cap (spill-proof; grid caps at 1 block/CU).
// Rest = R22 champion: pack -> bf16 GEMM (gload_lds, swizzle) -> bf16 partials
// -> reduce. NT hints dead (R20/R24), atomics dead (R4/R10/R21).

#define M_T 512
#define N_T 2048
#define K_T 4096
#define NGRP 16
#define BM 256
#define BN 128
#define BK 64
#define OUT_ELEMS (M_T * N_T)
#define W_ELEMS (N_T * K_T)          // 8388608 bf16
#define X_ELEMS (M_T * K_T)          // 2097152 bf16

typedef __attribute__((ext_vector_type(8))) short mfrag_t;           // 8 bf16 (4 VGPR)
typedef __attribute__((ext_vector_type(8))) unsigned short u16x8;
typedef __attribute__((ext_vector_type(4))) float f32x4;

__device__ __forceinline__ unsigned short f2bf(float f) {
  union { __hip_bfloat16 h; unsigned short u; } c;
  c.h = __float2bfloat16(f);
  return c.u;
}

__device__ __forceinline__ float bf2f(unsigned short u) {
  union { unsigned int i; float f; } c;
  c.i = ((unsigned int)u) << 16;
  return c.f;
}

// ---- pass 1: dequant W (int32 q -> bf16) + cast X (fp32 -> bf16) ----
__global__ __launch_bounds__(256) void pack_kernel(
    const float* __restrict__ x, const int* __restrict__ qw,
    const float* __restrict__ qrange, const float* __restrict__ qmin,
    unsigned short* __restrict__ wsW, unsigned short* __restrict__ wsX) {
  const int bid = blockIdx.x;
  const int tid = threadIdx.x;
  if (bid < (W_ELEMS / 8) / 256) {
    const int gidx = bid * 256 + tid;        // [0, 1048576)
    const int o = gidx >> 9;                 // 512 groups-of-8 per row
    const int k8 = gidx & 511;
    const int g = k8 >> 5;                   // 32 groups-of-8 per quant group
    const float sc = qrange[o * NGRP + g];
    const float mn = qmin[o * NGRP + g];
    const int4* q = (const int4*)(qw + ((size_t)o << 12) + (k8 << 3));
    const int4 q0 = q[0], q1 = q[1];
    u16x8 p;
    p[0] = f2bf((float)q0.x * sc + mn); p[1] = f2bf((float)q0.y * sc + mn);
    p[2] = f2bf((float)q0.z * sc + mn); p[3] = f2bf((float)q0.w * sc + mn);
    p[4] = f2bf((float)q1.x * sc + mn); p[5] = f2bf((float)q1.y * sc + mn);
    p[6] = f2bf((float)q1.z * sc + mn); p[7] = f2bf((float)q1.w * sc + mn);
    *(u16x8*)(wsW + ((size_t)gidx << 3)) = p;
  } else {
    const int gidx = (bid - (W_ELEMS / 8) / 256) * 256 + tid;  // [0, 262144)
    const float4* a = (const float4*)(x + ((size_t)gidx << 3));
    const float4 a0 = a[0], a1 = a[1];
    u16x8 p;
    p[0] = f2bf(a0.x); p[1] = f2bf(a0.y); p[2] = f2bf(a0.z); p[3] = f2bf(a0.w);
    p[4] = f2bf(a1.x); p[5] = f2bf(a1.y); p[6] = f2bf(a1.z); p[7] = f2bf(a1.w);
    *(u16x8*)(wsX + ((size_t)gidx << 3)) = p;
  }
}

// ---- pass 2: bf16 GEMM, BM=256 tiles, gload_lds, bf16 partial stores ----
template <int KSPLIT>
__global__ __launch_bounds__(512, 2) void dq_gemm_kernel(
    const unsigned short* __restrict__ wsX, const unsigned short* __restrict__ wsW,
    unsigned short* __restrict__ dst) {
  constexpr int KC = K_T / KSPLIT;
  constexpr int NTC = KC / BK;

  // physical layout: [row][slot^(row&7)], slot = 8-elem (16B) unit; linear fill
  __shared__ __align__(16) unsigned short As[BM * BK];   // 32KB
  __shared__ __align__(16) unsigned short Bs[BN * BK];   // 16KB

  const int tid = threadIdx.x;
  const int b = blockIdx.x;
  const int kc = b & 7;                 // XCD id == k-chunk (b%8 round-robin)
  const int slot = b >> 3;              // 0..31
  const int xt = slot & 15;             // n-tile (16)
  const int yt = slot >> 4;             // m-tile (2)
  const int n0 = xt * BN;
  const int m0 = yt * BM;
  const int kbase = kc * KC;

  const int lane = tid & 63;
  const int wv = tid >> 6;              // 0..7

  // compute mapping: 8 waves 4(M) x 2(N); wave tile 64x64 (4x4 frags)
  const int wm = (wv >> 1) * 64;        // 0,64,128,192
  const int wn = (wv & 1) * 64;         // 0,64
  const int lr = lane & 15;
  const int lq = lane >> 4;
  const int rxl = lr & 7;               // read-side xor (row&7 == lr&7)

  // staging (gload_lds 16B/lane): lane l -> row = base + (l>>3), slot = l&7;
  // global source col16 = (l&7) ^ (l>>3) (inverse swizzle; dest linear).
  // A: wave wv covers rows [wv*32, wv*32+32) = 4 chunks of 8 rows.
  // B: wave wv covers rows [wv*16, wv*16+16) = 2 chunks of 8 rows.
  const int srow8 = lane >> 3;          // 0..7
  const int scol = (((lane & 7) ^ srow8) << 3);
  const unsigned short* gA = wsX + (size_t)(m0 + wv * 32 + srow8) * K_T + kbase + scol;
  const unsigned short* gB = wsW + (size_t)(n0 + wv * 16 + srow8) * K_T + kbase + scol;
  unsigned short* lA = &As[wv * 32 * BK];
  unsigned short* lB = &Bs[wv * 16 * BK];

#define STAGE(T)                                                              \
  do {                                                                        \
    const size_t o_ = (size_t)(T) * BK;                                       \
    _Pragma("unroll")                                                         \
    for (int c_ = 0; c_ < 4; ++c_)                                            \
      __builtin_amdgcn_global_load_lds(                                       \
          (const __attribute__((address_space(1))) void*)(gA + o_ + (size_t)c_ * 8 * K_T), \
          (__attribute__((address_space(3))) void*)(lA + c_ * 8 * BK), 16, 0, 0); \
    _Pragma("unroll")                                                         \
    for (int c_ = 0; c_ < 2; ++c_)                                            \
      __builtin_amdgcn_global_load_lds(                                       \
          (const __attribute__((address_space(1))) void*)(gB + o_ + (size_t)c_ * 8 * K_T), \
          (__attribute__((address_space(3))) void*)(lB + c_ * 8 * BK), 16, 0, 0); \
  } while (0)

  f32x4 acc[4][4] = {};

  STAGE(0);
  for (int t = 0; t < NTC; ++t) {
    __syncthreads();  // drains vmcnt(0): staged tile visible to all waves

#pragma unroll
    for (int kk = 0; kk < 2; ++kk) {
      const int so = ((kk * 4 + lq) ^ rxl) << 3;
      mfrag_t af[4], bf[4];
#pragma unroll
      for (int fm = 0; fm < 4; ++fm)
        af[fm] = *(const mfrag_t*)&As[(wm + fm * 16 + lr) * BK + so];
#pragma unroll
      for (int fn = 0; fn < 4; ++fn)
        bf[fn] = *(const mfrag_t*)&Bs[(wn + fn * 16 + lr) * BK + so];
#pragma unroll
      for (int fm = 0; fm < 4; ++fm)
#pragma unroll
        for (int fn = 0; fn < 4; ++fn)
          acc[fm][fn] = __builtin_amdgcn_mfma_f32_16x16x32_bf16(af[fm], bf[fn], acc[fm][fn], 0, 0, 0);
    }

    if (t + 1 < NTC) {
      __syncthreads();  // all waves done reading before overwrite
      STAGE(t + 1);
    }
  }
#undef STAGE

  // ---- epilogue: bf16 partial stores to ws slice ----
  // C/D layout col=lane&15, row=(lane>>4)*4+reg (measured m89/m91)
  unsigned short* base = dst + (size_t)kc * OUT_ELEMS;
#pragma unroll
  for (int fm = 0; fm < 4; ++fm) {
#pragma unroll
    for (int fn = 0; fn < 4; ++fn) {
      const int rr = m0 + wm + fm * 16 + lq * 4;
      const int c = n0 + wn + fn * 16 + lr;
      unsigned short* op = base + (size_t)rr * N_T + c;
      op[0 * (size_t)N_T] = f2bf(acc[fm][fn][0]);
      op[1 * (size_t)N_T] = f2bf(acc[fm][fn][1]);
      op[2 * (size_t)N_T] = f2bf(acc[fm][fn][2]);
      op[3 * (size_t)N_T] = f2bf(acc[fm][fn][3]);
    }
  }
}

// ---- pass 3: out[i] = sum_s bf16 partials[s][i], fp32 accum, fixed order ----
template <int KSPLIT>
__global__ __launch_bounds__(256) void reduce_kernel(const unsigned short* __restrict__ ws,
                                                     float* __restrict__ out) {
  const int i8 = blockIdx.x * 256 + threadIdx.x;   // 8 elems per thread
  const size_t base = (size_t)i8 * 8;
  float s[8];
  {
    const u16x8 v = *(const u16x8*)(ws + base);
#pragma unroll
    for (int j = 0; j < 8; ++j) s[j] = bf2f(v[j]);
  }
#pragma unroll
  for (int sl = 1; sl < KSPLIT; ++sl) {
    const u16x8 v = *(const u16x8*)(ws + (size_t)sl * OUT_ELEMS + base);
#pragma unroll
    for (int j = 0; j < 8; ++j) s[j] += bf2f(v[j]);
  }
  float4* o = (float4*)(out + base);
  o[0] = make_float4(s[0], s[1], s[2], s[3]);
  o[1] = make_float4(s[4], s[5], s[6], s[7]);
}

// ---- fallback only (never expected to run): naive dot per output elem ----
__global__ void naive_kernel(const float* __restrict__ x, const int* __restrict__ qw,
                             const float* __restrict__ qrange, const float* __restrict__ qmin,
                             float* __restrict__ out) {
  const int idx = blockIdx.x * 256 + threadIdx.x;
  if (idx >= OUT_ELEMS) return;
  const int m = idx / N_T, n = idx % N_T;
  float s = 0.f;
  for (int g = 0; g < NGRP; ++g) {
    const float sc = qrange[n * NGRP + g], mn = qmin[n * NGRP + g];
    float d = 0.f, xs = 0.f;
    for (int k = g * 256; k < (g + 1) * 256; ++k) {
      d += x[(size_t)m * K_T + k] * (float)qw[(size_t)n * K_T + k];
      xs += x[(size_t)m * K_T + k];
    }
    s += d * sc + xs * mn;
  }
  out[idx] = s;
}

extern "C" void kernel_launch(void* const* d_in, const int* in_sizes, int n_in,
                              void* d_out, int out_size, void* d_ws, size_t ws_size,
                              hipStream_t stream) {
  const float* x = (const float*)d_in[0];
  const int* qw = (const int*)d_in[1];
  const float* qr = (const float*)d_in[2];
  const float* qm = (const float*)d_in[3];
  float* out = (float*)d_out;

  constexpr int KS = 8;
  unsigned short* wsW = (unsigned short*)d_ws;
  unsigned short* wsX = wsW + W_ELEMS;
  unsigned short* partials = wsX + X_ELEMS;
  const size_t need = (size_t)W_ELEMS * 2 + (size_t)X_ELEMS * 2 +
                      (size_t)KS * OUT_ELEMS * 2;
  if (ws_size >= need) {
    const int packblk = (W_ELEMS / 8) / 256 + (X_ELEMS / 8) / 256;  // 4096+1024
    pack_kernel<<<packblk, 256, 0, stream>>>(x, qw, qr, qm, wsW, wsX);
    const int nblk = (N_T / BN) * (M_T / BM) * KS;  // 16*2*8 = 256
    dq_gemm_kernel<KS><<<nblk, dim3(512, 1, 1), 0, stream>>>(wsX, wsW, partials);
    reduce_kernel<KS><<<OUT_ELEMS / 8 / 256, 256, 0, stream>>>(partials, out);
  } else {
    naive_kernel<<<(OUT_ELEMS + 255) / 256, 256, 0, stream>>>(x, qw, qr, qm, out);
  }
}

// Round 27
// 32.775 us; speedup vs baseline: 1.0660x; 1.0551x over previous
//
#include <hip/hip_runtime.h>
#include <hip/hip_bf16.h>

// InferenceLinear: out[m][n] = sum_k x[m][k] * (q[n][k]*qrange[n][k/256] + qmin[n][k/256])
// M=512, N=2048, K=4096, 16 groups of 256.
// R26 resubmit (infra failure, no signal). int8-W path: pack W as RAW int8
// (33.5->8.4MB write; no dequant in pack); GEMM stages B reg-staged with fused
// dequant (R2/R8-proven pattern, identical math/absmax to R22), A stays
// gload_lds. B HBM/L2 bytes halve vs bf16. Rest = champion: X->bf16 pack,
// 128x128 BK=64 KSPLIT=8 XCD decode, swizzled LDS, bf16 partials -> reduce.
// Dead levers: atomics, NT, BM=256, 1-blk/CU.

#define M_T 512
#define N_T 2048
#define K_T 4096
#define NGRP 16
#define BM 128
#define BN 128
#define BK 64
#define OUT_ELEMS (M_T * N_T)
#define W_ELEMS (N_T * K_T)          // 8388608
#define X_ELEMS (M_T * K_T)          // 2097152

typedef __attribute__((ext_vector_type(8))) short mfrag_t;           // 8 bf16 (4 VGPR)
typedef __attribute__((ext_vector_type(8))) unsigned short u16x8;
typedef __attribute__((ext_vector_type(4))) float f32x4;

__device__ __forceinline__ unsigned short f2bf(float f) {
  union { __hip_bfloat16 h; unsigned short u; } c;
  c.h = __float2bfloat16(f);
  return c.u;
}

__device__ __forceinline__ float bf2f(unsigned short u) {
  union { unsigned int i; float f; } c;
  c.i = ((unsigned int)u) << 16;
  return c.f;
}

// ---- pass 1: compress W (int32 -> raw uint8) + cast X (fp32 -> bf16) ----
__global__ __launch_bounds__(256) void pack_kernel(
    const float* __restrict__ x, const int* __restrict__ qw,
    unsigned char* __restrict__ wsW8, unsigned short* __restrict__ wsX) {
  const int bid = blockIdx.x;
  const int tid = threadIdx.x;
  if (bid < (W_ELEMS / 8) / 256) {
    const int gidx = bid * 256 + tid;        // [0, 1048576), 8 elems each
    const int4* q = (const int4*)(qw + ((size_t)gidx << 3));
    const int4 q0 = q[0], q1 = q[1];
    unsigned int w0 = (unsigned)(q0.x & 255) | ((unsigned)(q0.y & 255) << 8) |
                      ((unsigned)(q0.z & 255) << 16) | ((unsigned)(q0.w & 255) << 24);
    unsigned int w1 = (unsigned)(q1.x & 255) | ((unsigned)(q1.y & 255) << 8) |
                      ((unsigned)(q1.z & 255) << 16) | ((unsigned)(q1.w & 255) << 24);
    uint2* o = (uint2*)(wsW8 + ((size_t)gidx << 3));
    *o = make_uint2(w0, w1);
  } else {
    const int gidx = (bid - (W_ELEMS / 8) / 256) * 256 + tid;  // [0, 262144)
    const float4* a = (const float4*)(x + ((size_t)gidx << 3));
    const float4 a0 = a[0], a1 = a[1];
    u16x8 p;
    p[0] = f2bf(a0.x); p[1] = f2bf(a0.y); p[2] = f2bf(a0.z); p[3] = f2bf(a0.w);
    p[4] = f2bf(a1.x); p[5] = f2bf(a1.y); p[6] = f2bf(a1.z); p[7] = f2bf(a1.w);
    *(u16x8*)(wsX + ((size_t)gidx << 3)) = p;
  }
}

// ---- pass 2: GEMM. A: gload_lds bf16. B: reg-staged int8 + fused dequant ----
template <int KSPLIT>
__global__ __launch_bounds__(512, 4) void dq_gemm_kernel(
    const unsigned short* __restrict__ wsX, const unsigned char* __restrict__ wsW8,
    const float* __restrict__ qrange, const float* __restrict__ qmin,
    unsigned short* __restrict__ dst) {
  constexpr int KC = K_T / KSPLIT;      // 512 (= 2 quant groups)
  constexpr int NTC = KC / BK;          // 8

  // physical layout: [row][slot^(row&7)], slot = 8-elem (16B) unit
  __shared__ __align__(16) unsigned short As[BM * BK];
  __shared__ __align__(16) unsigned short Bs[BN * BK];

  const int tid = threadIdx.x;
  const int b = blockIdx.x;
  const int kc = b & 7;                 // XCD id == k-chunk (b%8 round-robin)
  const int slot = b >> 3;
  const int xt = slot & 15;             // n-tile
  const int yt = slot >> 4;             // m-tile
  const int n0 = xt * BN;
  const int m0 = yt * BM;
  const int kbase = kc * KC;

  const int lane = tid & 63;
  const int wv = tid >> 6;              // 0..7

  // compute mapping: 8 waves 2(M) x 4(N); wave tile 64x32 (4x2 frags)
  const int wm = (wv >> 2) * 64;
  const int wn = (wv & 3) * 32;
  const int lr = lane & 15;
  const int lq = lane >> 4;
  const int rxl = lr & 7;               // read-side xor (row&7 == lr&7)

  // ---- A staging via gload_lds (16B/lane), inverse-swizzled source ----
  const int swzcol = (((lane & 7) ^ (lane >> 3)) << 3);
  const int r0 = wv * 16 + (lane >> 3);
  const int r1 = r0 + 8;
  const unsigned short* gA0 = wsX + (size_t)(m0 + r0) * K_T + kbase + swzcol;
  const unsigned short* gA1 = wsX + (size_t)(m0 + r1) * K_T + kbase + swzcol;
  unsigned short* lA0 = &As[wv * 1024];
  unsigned short* lA1 = &As[wv * 1024 + 512];

#define STAGE_A(T)                                                            \
  do {                                                                        \
    const size_t o_ = (size_t)(T) * BK;                                       \
    __builtin_amdgcn_global_load_lds(                                         \
        (const __attribute__((address_space(1))) void*)(gA0 + o_),            \
        (__attribute__((address_space(3))) void*)lA0, 16, 0, 0);              \
    __builtin_amdgcn_global_load_lds(                                         \
        (const __attribute__((address_space(1))) void*)(gA1 + o_),            \
        (__attribute__((address_space(3))) void*)lA1, 16, 0, 0);              \
  } while (0)

  // ---- B staging: thread -> (row = tid>>2 in [0,128), seg = tid&3 of 16) ----
  const int srow = tid >> 2;
  const int sseg = tid & 3;
  const unsigned char* qp8 = wsW8 + (size_t)(n0 + srow) * K_T + kbase + sseg * 16;
  const float* qrp = qrange + (size_t)(n0 + srow) * NGRP;
  const float* qmp = qmin + (size_t)(n0 + srow) * NGRP;
  const int rx7 = srow & 7;
  const int abase = srow * BK;
  const int wslot0 = ((sseg * 2) ^ rx7) << 3;
  const int wslot1 = ((sseg * 2 + 1) ^ rx7) << 3;

  uint4 bq;
  float sc, mn;
  // prologue: B(0) regs + scales, A(0) staged
  bq = *(const uint4*)(qp8);
  sc = qrp[kc * 2];
  mn = qmp[kc * 2];
  STAGE_A(0);

  f32x4 acc[4][2] = {};

#define DQW(W, P, J0)                                                         \
  P[J0 + 0] = f2bf((float)((W) & 255u) * sc + mn);                            \
  P[J0 + 1] = f2bf((float)(((W) >> 8) & 255u) * sc + mn);                     \
  P[J0 + 2] = f2bf((float)(((W) >> 16) & 255u) * sc + mn);                    \
  P[J0 + 3] = f2bf((float)(((W) >> 24) & 255u) * sc + mn)

  for (int t = 0; t < NTC; ++t) {
    // ---- stage B(t): dequant 16 int8 -> bf16 -> swizzled LDS ----
    {
      u16x8 pb0, pb1;
      DQW(bq.x, pb0, 0);
      DQW(bq.y, pb0, 4);
      DQW(bq.z, pb1, 0);
      DQW(bq.w, pb1, 4);
      *(u16x8*)&Bs[abase + wslot0] = pb0;
      *(u16x8*)&Bs[abase + wslot1] = pb1;
    }
    // ---- prefetch B(t+1) regs + scales (consumed next iter) ----
    if (t + 1 < NTC) {
      bq = *(const uint4*)(qp8 + (size_t)(t + 1) * BK);
      const int g = kc * 2 + ((t + 1) >> 2);   // group = 4 tiles of 64
      sc = qrp[g];
      mn = qmp[g];
    }

    __syncthreads();  // B ds_writes visible + A gload_lds drained (vmcnt 0)

    // ---- compute tile t ----
#pragma unroll
    for (int kk = 0; kk < 2; ++kk) {
      const int so = ((kk * 4 + lq) ^ rxl) << 3;
      mfrag_t af[4], bf[2];
#pragma unroll
      for (int fm = 0; fm < 4; ++fm)
        af[fm] = *(const mfrag_t*)&As[(wm + fm * 16 + lr) * BK + so];
#pragma unroll
      for (int fn = 0; fn < 2; ++fn)
        bf[fn] = *(const mfrag_t*)&Bs[(wn + fn * 16 + lr) * BK + so];
#pragma unroll
      for (int fm = 0; fm < 4; ++fm)
#pragma unroll
        for (int fn = 0; fn < 2; ++fn)
          acc[fm][fn] = __builtin_amdgcn_mfma_f32_16x16x32_bf16(af[fm], bf[fn], acc[fm][fn], 0, 0, 0);
    }

    if (t + 1 < NTC) {
      __syncthreads();  // all waves done reading before overwrite
      STAGE_A(t + 1);
    }
  }
#undef STAGE_A
#undef DQW

  // ---- epilogue: bf16 partial stores. C/D: col=lane&15, row=(lane>>4)*4+reg ----
  unsigned short* base = dst + (size_t)kc * OUT_ELEMS;
#pragma unroll
  for (int fm = 0; fm < 4; ++fm) {
#pragma unroll
    for (int fn = 0; fn < 2; ++fn) {
      const int rr = m0 + wm + fm * 16 + lq * 4;
      const int c = n0 + wn + fn * 16 + lr;
      unsigned short* op = base + (size_t)rr * N_T + c;
      op[0 * (size_t)N_T] = f2bf(acc[fm][fn][0]);
      op[1 * (size_t)N_T] = f2bf(acc[fm][fn][1]);
      op[2 * (size_t)N_T] = f2bf(acc[fm][fn][2]);
      op[3 * (size_t)N_T] = f2bf(acc[fm][fn][3]);
    }
  }
}

// ---- pass 3: out[i] = sum_s bf16 partials[s][i], fp32 accum, fixed order ----
template <int KSPLIT>
__global__ __launch_bounds__(256) void reduce_kernel(const unsigned short* __restrict__ ws,
                                                     float* __restrict__ out) {
  const int i8 = blockIdx.x * 256 + threadIdx.x;   // 8 elems per thread
  const size_t base = (size_t)i8 * 8;
  float s[8];
  {
    const u16x8 v = *(const u16x8*)(ws + base);
#pragma unroll
    for (int j = 0; j < 8; ++j) s[j] = bf2f(v[j]);
  }
#pragma unroll
  for (int sl = 1; sl < KSPLIT; ++sl) {
    const u16x8 v = *(const u16x8*)(ws + (size_t)sl * OUT_ELEMS + base);
#pragma unroll
    for (int j = 0; j < 8; ++j) s[j] += bf2f(v[j]);
  }
  float4* o = (float4*)(out + base);
  o[0] = make_float4(s[0], s[1], s[2], s[3]);
  o[1] = make_float4(s[4], s[5], s[6], s[7]);
}

// ---- fallback only (never expected to run): naive dot per output elem ----
__global__ void naive_kernel(const float* __restrict__ x, const int* __restrict__ qw,
                             const float* __restrict__ qrange, const float* __restrict__ qmin,
                             float* __restrict__ out) {
  const int idx = blockIdx.x * 256 + threadIdx.x;
  if (idx >= OUT_ELEMS) return;
  const int m = idx / N_T, n = idx % N_T;
  float s = 0.f;
  for (int g = 0; g < NGRP; ++g) {
    const float sc = qrange[n * NGRP + g], mn = qmin[n * NGRP + g];
    float d = 0.f, xs = 0.f;
    for (int k = g * 256; k < (g + 1) * 256; ++k) {
      d += x[(size_t)m * K_T + k] * (float)qw[(size_t)n * K_T + k];
      xs += x[(size_t)m * K_T + k];
    }
    s += d * sc + xs * mn;
  }
  out[idx] = s;
}

extern "C" void kernel_launch(void* const* d_in, const int* in_sizes, int n_in,
                              void* d_out, int out_size, void* d_ws, size_t ws_size,
                              hipStream_t stream) {
  const float* x = (const float*)d_in[0];
  const int* qw = (const int*)d_in[1];
  const float* qr = (const float*)d_in[2];
  const float* qm = (const float*)d_in[3];
  float* out = (float*)d_out;

  constexpr int KS = 8;
  unsigned char* wsW8 = (unsigned char*)d_ws;
  unsigned short* wsX = (unsigned short*)(wsW8 + W_ELEMS);
  unsigned short* partials = wsX + X_ELEMS;
  const size_t need = (size_t)W_ELEMS + (size_t)X_ELEMS * 2 +
                      (size_t)KS * OUT_ELEMS * 2;
  if (ws_size >= need) {
    const int packblk = (W_ELEMS / 8) / 256 + (X_ELEMS / 8) / 256;  // 4096+1024
    pack_kernel<<<packblk, 256, 0, stream>>>(x, qw, wsW8, wsX);
    const int nblk = (N_T / BN) * (M_T / BM) * KS;  // 512
    dq_gemm_kernel<KS><<<nblk, dim3(512, 1, 1), 0, stream>>>(wsX, wsW8, qr, qm, partials);
    reduce_kernel<KS><<<OUT_ELEMS / 8 / 256, 256, 0, stream>>>(partials, out);
  } else {
    naive_kernel<<<(OUT_ELEMS + 255) / 256, 256, 0, stream>>>(x, qw, qr, qm, out);
  }
}

// Round 28
// 32.300 us; speedup vs baseline: 1.0817x; 1.0147x over previous
//
#include <hip/hip_runtime.h>
#include <hip/hip_bf16.h>

// InferenceLinear: out[m][n] = sum_k x[m][k] * (q[n][k]*qrange[n][k/256] + qmin[n][k/256])
// M=512, N=2048, K=4096, 16 groups of 256.
// R28 = champion restoration (R22, 32.24us measured). R26's int8-W was neutral-
// to-worse (32.77): conversion work is conserved between pack and GEMM (4th
// confirmation). Final structure: pack (dequant W->bf16 + cast X->bf16, HBM
// roofline) -> bf16 MFMA GEMM (128x128, BK=64, KSPLIT=8, XCD decode kc=b&7,
// gload_lds w/ inverse-swizzled source, swizzled LDS, 2-barrier loop) -> bf16
// partials -> deterministic reduce. Dead levers: atomics (R4/R10/R21), NT hints
// (R20/R24), 1-blk/CU tiles (R17/R25), B-byte cuts (R26), schedule variants
// (R11/R14/R15/R16), occupancy (R6).

#define M_T 512
#define N_T 2048
#define K_T 4096
#define NGRP 16
#define BM 128
#define BN 128
#define BK 64
#define OUT_ELEMS (M_T * N_T)
#define W_ELEMS (N_T * K_T)          // 8388608 bf16
#define X_ELEMS (M_T * K_T)          // 2097152 bf16

typedef __attribute__((ext_vector_type(8))) short mfrag_t;           // 8 bf16 (4 VGPR)
typedef __attribute__((ext_vector_type(8))) unsigned short u16x8;
typedef __attribute__((ext_vector_type(4))) float f32x4;

__device__ __forceinline__ unsigned short f2bf(float f) {
  union { __hip_bfloat16 h; unsigned short u; } c;
  c.h = __float2bfloat16(f);
  return c.u;
}

__device__ __forceinline__ float bf2f(unsigned short u) {
  union { unsigned int i; float f; } c;
  c.i = ((unsigned int)u) << 16;
  return c.f;
}

// ---- pass 1: dequant W (int32 q -> bf16) + cast X (fp32 -> bf16) ----
__global__ __launch_bounds__(256) void pack_kernel(
    const float* __restrict__ x, const int* __restrict__ qw,
    const float* __restrict__ qrange, const float* __restrict__ qmin,
    unsigned short* __restrict__ wsW, unsigned short* __restrict__ wsX) {
  const int bid = blockIdx.x;
  const int tid = threadIdx.x;
  if (bid < (W_ELEMS / 8) / 256) {
    const int gidx = bid * 256 + tid;        // [0, 1048576)
    const int o = gidx >> 9;                 // 512 groups-of-8 per row
    const int k8 = gidx & 511;
    const int g = k8 >> 5;                   // 32 groups-of-8 per quant group
    const float sc = qrange[o * NGRP + g];
    const float mn = qmin[o * NGRP + g];
    const int4* q = (const int4*)(qw + ((size_t)o << 12) + (k8 << 3));
    const int4 q0 = q[0], q1 = q[1];
    u16x8 p;
    p[0] = f2bf((float)q0.x * sc + mn); p[1] = f2bf((float)q0.y * sc + mn);
    p[2] = f2bf((float)q0.z * sc + mn); p[3] = f2bf((float)q0.w * sc + mn);
    p[4] = f2bf((float)q1.x * sc + mn); p[5] = f2bf((float)q1.y * sc + mn);
    p[6] = f2bf((float)q1.z * sc + mn); p[7] = f2bf((float)q1.w * sc + mn);
    *(u16x8*)(wsW + ((size_t)gidx << 3)) = p;
  } else {
    const int gidx = (bid - (W_ELEMS / 8) / 256) * 256 + tid;  // [0, 262144)
    const float4* a = (const float4*)(x + ((size_t)gidx << 3));
    const float4 a0 = a[0], a1 = a[1];
    u16x8 p;
    p[0] = f2bf(a0.x); p[1] = f2bf(a0.y); p[2] = f2bf(a0.z); p[3] = f2bf(a0.w);
    p[4] = f2bf(a1.x); p[5] = f2bf(a1.y); p[6] = f2bf(a1.z); p[7] = f2bf(a1.w);
    *(u16x8*)(wsX + ((size_t)gidx << 3)) = p;
  }
}

// ---- pass 2: bf16 GEMM with global_load_lds staging; bf16 partial stores ----
template <int KSPLIT, bool XCDSWZ>
__global__ __launch_bounds__(512, 4) void dq_gemm_kernel(
    const unsigned short* __restrict__ wsX, const unsigned short* __restrict__ wsW,
    unsigned short* __restrict__ dst) {
  constexpr int KC = K_T / KSPLIT;
  constexpr int NTC = KC / BK;

  // physical layout: [row][slot^(row&7)], slot = 8-elem (16B) unit; linear fill
  __shared__ __align__(16) unsigned short As[BM * BK];
  __shared__ __align__(16) unsigned short Bs[BN * BK];

  const int tid = threadIdx.x;
  int xt, yt, kc;
  if (XCDSWZ) {
    const int b = blockIdx.x;
    kc = b & 7;                 // XCD id == k-chunk (assumes b%8 round-robin)
    const int slot = b >> 3;
    xt = slot & 15;             // n-tile
    yt = slot >> 4;             // m-tile
  } else {
    const int b = blockIdx.x;
    xt = b & 15;
    yt = (b >> 4) & 3;
    kc = b >> 6;
  }
  const int n0 = xt * BN;
  const int m0 = yt * BM;
  const int kbase = kc * KC;

  // compute mapping: 8 waves, 2(M) x 4(N); wave tile 64x32
  const int lane = tid & 63;
  const int wv = tid >> 6;
  const int wm = (wv >> 2) * 64;   // 0,64
  const int wn = (wv & 3) * 32;    // 0,32,64,96
  const int lr = lane & 15;
  const int lq = lane >> 4;
  const int rxl = lr & 7;  // read-side xor (row&7 == lr&7: wm,wn,f*16 mult of 8)

  // staging mapping for global_load_lds (16B/lane): wave wv covers rows
  // [wv*16, wv*16+16) in two 1KB chunks (8 rows each). lane l -> row += l>>3,
  // phys slot = l&7. LDS[row][p] holds logical data[p ^ (row&7)]; row&7 == l>>3,
  // so per-lane GLOBAL source col16 = (l&7) ^ (l>>3). Dest linear = base+lane*16.
  const int swzcol = (((lane & 7) ^ (lane >> 3)) << 3);       // elem offset
  const int r0 = wv * 16 + (lane >> 3);                        // chunk0 row
  const int r1 = r0 + 8;                                       // chunk1 row
  const unsigned short* gA0 = wsX + (size_t)(m0 + r0) * K_T + kbase + swzcol;
  const unsigned short* gA1 = wsX + (size_t)(m0 + r1) * K_T + kbase + swzcol;
  const unsigned short* gB0 = wsW + (size_t)(n0 + r0) * K_T + kbase + swzcol;
  const unsigned short* gB1 = wsW + (size_t)(n0 + r1) * K_T + kbase + swzcol;
  unsigned short* lA0 = &As[wv * 1024];        // elems; 2KB per wave
  unsigned short* lA1 = &As[wv * 1024 + 512];
  unsigned short* lB0 = &Bs[wv * 1024];
  unsigned short* lB1 = &Bs[wv * 1024 + 512];

#define STAGE(T)                                                              \
  do {                                                                        \
    const size_t o_ = (size_t)(T) * BK;                                       \
    __builtin_amdgcn_global_load_lds(                                         \
        (const __attribute__((address_space(1))) void*)(gA0 + o_),            \
        (__attribute__((address_space(3))) void*)lA0, 16, 0, 0);              \
    __builtin_amdgcn_global_load_lds(                                         \
        (const __attribute__((address_space(1))) void*)(gA1 + o_),            \
        (__attribute__((address_space(3))) void*)lA1, 16, 0, 0);              \
    __builtin_amdgcn_global_load_lds(                                         \
        (const __attribute__((address_space(1))) void*)(gB0 + o_),            \
        (__attribute__((address_space(3))) void*)lB0, 16, 0, 0);              \
    __builtin_amdgcn_global_load_lds(                                         \
        (const __attribute__((address_space(1))) void*)(gB1 + o_),            \
        (__attribute__((address_space(3))) void*)lB1, 16, 0, 0);              \
  } while (0)

  f32x4 acc[4][2] = {};

  STAGE(0);
  for (int t = 0; t < NTC; ++t) {
    __syncthreads();  // drains vmcnt(0): staged tile visible to all waves

#pragma unroll
    for (int kk = 0; kk < 2; ++kk) {
      const int so = ((kk * 4 + lq) ^ rxl) << 3;
      mfrag_t af[4], bf[2];
#pragma unroll
      for (int fm = 0; fm < 4; ++fm)
        af[fm] = *(const mfrag_t*)&As[(wm + fm * 16 + lr) * BK + so];
#pragma unroll
      for (int fn = 0; fn < 2; ++fn)
        bf[fn] = *(const mfrag_t*)&Bs[(wn + fn * 16 + lr) * BK + so];
#pragma unroll
      for (int fm = 0; fm < 4; ++fm)
#pragma unroll
        for (int fn = 0; fn < 2; ++fn)
          acc[fm][fn] = __builtin_amdgcn_mfma_f32_16x16x32_bf16(af[fm], bf[fn], acc[fm][fn], 0, 0, 0);
    }

    if (t + 1 < NTC) {
      __syncthreads();  // all waves done reading before overwrite
      STAGE(t + 1);
    }
  }
#undef STAGE

  // ---- epilogue: bf16 partial stores to ws slice (half the bytes) ----
  // C/D layout col=lane&15, row=(lane>>4)*4+reg (measured m89/m91)
  unsigned short* base = dst + (size_t)kc * OUT_ELEMS;
#pragma unroll
  for (int fm = 0; fm < 4; ++fm) {
#pragma unroll
    for (int fn = 0; fn < 2; ++fn) {
      const int rr = m0 + wm + fm * 16 + lq * 4;
      const int c = n0 + wn + fn * 16 + lr;
      unsigned short* op = base + (size_t)rr * N_T + c;
      op[0 * (size_t)N_T] = f2bf(acc[fm][fn][0]);
      op[1 * (size_t)N_T] = f2bf(acc[fm][fn][1]);
      op[2 * (size_t)N_T] = f2bf(acc[fm][fn][2]);
      op[3 * (size_t)N_T] = f2bf(acc[fm][fn][3]);
    }
  }
}

// ---- pass 3: out[i] = sum_s bf16 partials[s][i], fp32 accum, fixed order ----
template <int KSPLIT>
__global__ __launch_bounds__(256) void reduce_kernel(const unsigned short* __restrict__ ws,
                                                     float* __restrict__ out) {
  const int i8 = blockIdx.x * 256 + threadIdx.x;   // 8 elems per thread
  const size_t base = (size_t)i8 * 8;
  float s[8];
  {
    const u16x8 v = *(const u16x8*)(ws + base);
#pragma unroll
    for (int j = 0; j < 8; ++j) s[j] = bf2f(v[j]);
  }
#pragma unroll
  for (int sl = 1; sl < KSPLIT; ++sl) {
    const u16x8 v = *(const u16x8*)(ws + (size_t)sl * OUT_ELEMS + base);
#pragma unroll
    for (int j = 0; j < 8; ++j) s[j] += bf2f(v[j]);
  }
  float4* o = (float4*)(out + base);
  o[0] = make_float4(s[0], s[1], s[2], s[3]);
  o[1] = make_float4(s[4], s[5], s[6], s[7]);
}

// ---- fallback only (never expected to run): naive dot per output elem ----
__global__ void naive_kernel(const float* __restrict__ x, const int* __restrict__ qw,
                             const float* __restrict__ qrange, const float* __restrict__ qmin,
                             float* __restrict__ out) {
  const int idx = blockIdx.x * 256 + threadIdx.x;
  if (idx >= OUT_ELEMS) return;
  const int m = idx / N_T, n = idx % N_T;
  float s = 0.f;
  for (int g = 0; g < NGRP; ++g) {
    const float sc = qrange[n * NGRP + g], mn = qmin[n * NGRP + g];
    float d = 0.f, xs = 0.f;
    for (int k = g * 256; k < (g + 1) * 256; ++k) {
      d += x[(size_t)m * K_T + k] * (float)qw[(size_t)n * K_T + k];
      xs += x[(size_t)m * K_T + k];
    }
    s += d * sc + xs * mn;
  }
  out[idx] = s;
}

extern "C" void kernel_launch(void* const* d_in, const int* in_sizes, int n_in,
                              void* d_out, int out_size, void* d_ws, size_t ws_size,
                              hipStream_t stream) {
  const float* x = (const float*)d_in[0];
  const int* qw = (const int*)d_in[1];
  const float* qr = (const float*)d_in[2];
  const float* qm = (const float*)d_in[3];
  float* out = (float*)d_out;

  constexpr int KS = 8;
  unsigned short* wsW = (unsigned short*)d_ws;
  unsigned short* wsX = wsW + W_ELEMS;
  unsigned short* partials = wsX + X_ELEMS;
  const size_t need = (size_t)W_ELEMS * 2 + (size_t)X_ELEMS * 2 +
                      (size_t)KS * OUT_ELEMS * 2;
  if (ws_size >= need) {
    const int packblk = (W_ELEMS / 8) / 256 + (X_ELEMS / 8) / 256;  // 4096+1024
    pack_kernel<<<packblk, 256, 0, stream>>>(x, qw, qr, qm, wsW, wsX);
    const int nblk = (N_T / BN) * (M_T / BM) * KS;  // 512
    dq_gemm_kernel<KS, true><<<nblk, dim3(512, 1, 1), 0, stream>>>(wsX, wsW, partials);
    reduce_kernel<KS><<<OUT_ELEMS / 8 / 256, 256, 0, stream>>>(partials, out);
  } else {
    naive_kernel<<<(OUT_ELEMS + 255) / 256, 256, 0, stream>>>(x, qw, qr, qm, out);
  }
}